// Round 15
// baseline (34.768 us; speedup 1.0000x reference)
//
#include <hip/hip_runtime.h>

// ---- problem constants ----
#define IN_C  16
#define OUT_C 32
#define NB 2
#define TT 8
#define DD 8
#define HH 32
#define WW 32
#define TP 10
#define DP 10
#define HP 34
#define WPAD 34

// xt layout: [n][tp][dp][hp][icblk(2)][w(34)][ic8] bf16 ; row = 1088 B
#define XT_ROW_B  1088
#define XT_ELEMS  (NB*TP*DP*HP*2*WPAD*8)     // 3,699,200 bf16 = 7,398,400 B
// wt layout: [tap(84 padded)][icblk(2)][oc(32)][ic8] bf16 ; taps 81..83 zeroed
#define WT_TAPS_P 84
#define WT_ELEMS  (WT_TAPS_P*2*OUT_C*8)      // 43,008 bf16 = 86,016 B

typedef __bf16 bf16x8 __attribute__((ext_vector_type(8)));
typedef float  f32x4  __attribute__((ext_vector_type(4)));
typedef float  f32x16 __attribute__((ext_vector_type(16)));

__device__ __forceinline__ unsigned short f2bf(float f) {
    unsigned int u = __builtin_bit_cast(unsigned int, f);
    u += 0x7fffu + ((u >> 16) & 1u);       // RNE
    return (unsigned short)(u >> 16);
}

// ---------------- fused prep: xpose rows + halo zeroing + weight xform ----------------
__global__ __launch_bounds__(256) void prep_kernel(const float* __restrict__ x,
                                                   const float* __restrict__ wsrc,
                                                   unsigned short* __restrict__ xt,
                                                   unsigned short* __restrict__ wt) {
    int b = blockIdx.x;
    int tid = threadIdx.x;
    if (b < 4096) {
        __shared__ unsigned short ls[WW * IN_C];   // [w][c], 1 KiB
        int h = b & 31, d = (b >> 5) & 7, t = (b >> 8) & 7, n = b >> 11;
        int c = tid >> 5, w = tid & 31;
        float v0 = x[((((size_t)(n * IN_C + c)     * TT + t) * DD + d) * HH + h) * WW + w];
        float v1 = x[((((size_t)(n * IN_C + c + 8) * TT + t) * DD + d) * HH + h) * WW + w];
        ls[w * 16 + c]     = f2bf(v0);
        ls[w * 16 + c + 8] = f2bf(v1);
        __syncthreads();
        if (tid < 68) {                 // line = blk*34 + wl
            int blk = tid / 34, wl = tid % 34;
            unsigned char* row = (unsigned char*)xt +
                (size_t)(((n * TP + t + 1) * DP + d + 1) * HP + h + 1) * XT_ROW_B;
            f32x4 val = {0.f, 0.f, 0.f, 0.f};
            if (wl != 0 && wl != 33)
                val = *(const f32x4*)((const unsigned char*)ls + (wl - 1) * 32 + blk * 16);
            *(f32x4*)(row + tid * 16) = val;
        }
    } else if (b < 6800) {
        int j = b - 4096;               // 2704 halo rows
        int n, tp, dp, hp;
        if (j < 1360)      { n = j / 680;  int r = j % 680;  tp = (r / 340) * 9; int r2 = r % 340; dp = r2 / 34;       hp = r2 % 34; }
        else if (j < 2448) { int j2 = j - 1360; n = j2 / 544; int r = j2 % 544; tp = 1 + r / 68;  int r3 = r % 68;  dp = (r3 / 34) * 9; hp = r3 % 34; }
        else               { int j3 = j - 2448; n = j3 / 128; int r = j3 % 128; tp = 1 + r / 16;  int r4 = r % 16;  dp = 1 + r4 / 2;   hp = (r4 & 1) * 33; }
        if (tid < 68) {
            unsigned char* row = (unsigned char*)xt +
                (size_t)(((n * TP + tp) * DP + dp) * HP + hp) * XT_ROW_B;
            f32x4 z = {0.f, 0.f, 0.f, 0.f};
            *(f32x4*)(row + tid * 16) = z;
        }
    } else {
        int idx = (b - 6800) * 256 + tid;   // 0..43007
        int tap = idx >> 9;
        int r = idx & 511;
        int icblk = r >> 8, oc = (r >> 3) & 31, i8 = r & 7;
        int ic = icblk * 8 + i8;
        float v = (tap < 81) ? wsrc[(oc * IN_C + ic) * 81 + tap] : 0.0f;
        wt[idx] = f2bf(v);
    }
}

// ---------------- main: PURE-REGISTER dataflow (no LDS, no barriers) ----------------
// block = 2 waves (128 thr); wave owns 4 output h-rows (M_rep=4, acc[4] f32x16).
// Phase p = (kt,kd): A(p) = 18 frags (6 rows x 3 kw) ALREADY in registers
// (loaded global->VGPR one phase ahead; xt L2-resident, kw-shifts L1-hot);
// B chunk (27 taps/kt) in registers, reloaded at kt boundaries.
// One counted s_waitcnt vmcnt(18) per phase; zero LDS, zero __syncthreads.
// Grid 512 -> 2 blocks/CU.
__global__ __launch_bounds__(128) void conv_main_kernel(const unsigned short* __restrict__ xt,
                                                        const unsigned short* __restrict__ wt,
                                                        const float* __restrict__ bias,
                                                        float* __restrict__ out) {
    int bid = blockIdx.x;
    int lb  = (bid & 7) * 64 + (bid >> 3);   // XCD swizzle, bijective (512 % 8 == 0)
    int hb = lb & 3, d = (lb >> 2) & 7, t = (lb >> 5) & 7, n = lb >> 8;
    int h0 = hb * 8;
    int tid  = threadIdx.x;
    int wv   = tid >> 6;               // 0..1, owns output rows h0+4wv .. +3
    int lane = tid & 63;
    int l31  = lane & 31;
    int kblk = lane >> 5;

    const int rowbase = h0 + 4 * wv;   // first input row this wave touches

    bf16x8 a0[18], a1[18];             // A frag dbuf: [r*3+kw], static idx only
    bf16x8 bq[27];                     // current kt's B frags
    f32x16 acc[4];
#pragma unroll
    for (int m = 0; m < 4; ++m) acc[m] = {};

    // issue A(p) -> dst (18 global dwordx4)
    auto issueA = [&](int p, bf16x8 (&dst)[18]) {
        const unsigned char* base = (const unsigned char*)xt +
            (size_t)(((n * TP + t + p / 3) * DP + d + p % 3) * HP + rowbase) * XT_ROW_B +
            kblk * 544 + l31 * 16;
#pragma unroll
        for (int r = 0; r < 6; ++r)
#pragma unroll
            for (int kw = 0; kw < 3; ++kw)
                dst[r * 3 + kw] = *(const bf16x8*)(base + r * XT_ROW_B + kw * 16);
    };
    // issue B chunk kt (27 global dwordx4)
    auto issueB = [&](int kt) {
        const unsigned char* base = (const unsigned char*)wt +
            (size_t)kt * 27 * 1024 + kblk * 512 + l31 * 16;
#pragma unroll
        for (int j = 0; j < 27; ++j)
            bq[j] = *(const bf16x8*)(base + (size_t)j * 1024);
    };
    // 36 MFMAs for phase p from A regs + bq
    auto computeP = [&](const bf16x8 (&A)[18], int kd) {
#pragma unroll
        for (int kw = 0; kw < 3; ++kw)
#pragma unroll
            for (int kh = 0; kh < 3; ++kh)
#pragma unroll
                for (int m = 0; m < 4; ++m) {
                    const int r = m + kh;   // 0..5
                    acc[m] = __builtin_amdgcn_mfma_f32_32x32x16_bf16(
                        A[r * 3 + kw], bq[kd * 9 + kh * 3 + kw], acc[m], 0, 0, 0);
                }
    };

    // ---- prologue: queue = [A0(18), B0(27), A1(18)] ----
    issueA(0, a0);
    issueB(0);
    issueA(1, a1);

#pragma unroll
    for (int p = 0; p < 9; ++p) {
        // A(p) and B(kt(p)) are the oldest outstanding; newest 18 = A(p+1) may fly
        if (p < 8) asm volatile("s_waitcnt vmcnt(18)" ::: "memory");
        else       asm volatile("s_waitcnt vmcnt(0)"  ::: "memory");

        if ((p & 1) == 0) computeP(a0, p % 3); else computeP(a1, p % 3);

        if (p == 2) issueB(1);          // B before A: FIFO keeps vmcnt(18) exact
        if (p == 5) issueB(2);
        if (p <= 6) {
            if ((p & 1) == 0) issueA(p + 2, a0); else issueA(p + 2, a1);
        }
    }

    // ---- epilogue: col(oc)=l31, row(w)=(reg&3)+8*(reg>>2)+4*kblk ----
    float bsv = bias[l31];
#pragma unroll
    for (int m = 0; m < 4; ++m) {
        int oh = rowbase + m;
        float* obase = out + (((((size_t)n * OUT_C + l31) * TT + t) * DD + d) * HH + oh) * WW;
#pragma unroll
        for (int q = 0; q < 4; ++q) {
            f32x4 v = { acc[m][4 * q + 0] + bsv, acc[m][4 * q + 1] + bsv,
                        acc[m][4 * q + 2] + bsv, acc[m][4 * q + 3] + bsv };
            *(f32x4*)(obase + 8 * q + 4 * kblk) = v;
        }
    }
}

extern "C" void kernel_launch(void* const* d_in, const int* in_sizes, int n_in,
                              void* d_out, int out_size, void* d_ws, size_t ws_size,
                              hipStream_t stream) {
    const float* x    = (const float*)d_in[0];
    const float* wsrc = (const float*)d_in[1];
    const float* bias = (const float*)d_in[2];
    float* out        = (float*)d_out;

    unsigned short* xt = (unsigned short*)d_ws;
    unsigned short* wt = xt + XT_ELEMS;

    prep_kernel<<<4096 + 2704 + 164, 256, 0, stream>>>(x, wsrc, xt, wt);
    conv_main_kernel<<<NB * TT * DD * 4, 128, 0, stream>>>(xt, wt, bias, out);
}